// Round 1
// baseline (644.731 us; speedup 1.0000x reference)
//
#include <hip/hip_runtime.h>
#include <stdint.h>

#define T_STEPS 100
#define BATCH   256
#define NIN     784
#define NHID    512
#define NOUT    10

// ===========================================================================
// NUMERICS CONTRACT (validated PASS R5/R6/R7 — do not break):
//   * gemm1: per C element, fp32 single-accumulator fmaf chain, k ascending,
//     OpenBLAS kc=384 panel folds: C = ((P1 + P2) + P3) + bias, each +
//     a single __fadd_rn. Realized here as 2 launches:
//       P1:      C = acc(k 0..383)
//       P2+tail: C = fadd(fadd(fadd(C, acc(k 384..767)), acc(k 768..783)), b)
//     The P3 chain is computed row-at-a-time in the epilogue (8 regs), so the
//     per-element fp32 chains are bit-identical to the previous 3-launch
//     version (which was itself bit-identical to the single-kernel tot/acc).
//   * gemm2: f64 accumulation of fp32 products, +b2 in f64, single rounding.
//   * recurrences: fp32 _rn ops, ((0.95*mem + cur) - rst), no contraction;
//     spike/reset = (mem > 1.0f).
// PERF JOURNAL:
//   * R5 570us: 8x8 single-buf, VALUBusy 36%, latency-bound (2 waves/SIMD).
//   * R6 2144us: __launch_bounds__(256,3) clamped VGPR->84, scratch spill,
//     9.5 GB HBM. Never use min-waves arg near the register boundary.
//   * R7 453us: dbuf 8x4, VGPR 148, VALUBusy 38% — LDS-pipe bound:
//     3 b128/kk per 32 fma = 2.25x LDS oversubscription; also B-reads were
//     4-way bank conflicted (tn=(tid&15)*8 -> stride-8 banks).
//   * R8 582us: 3-launch panel split kills tot[] regs -> 8x8 micro, BK=8,
//     8x8 lane grid (lm=(lane&7)*8, ln=(lane>>3)*8: all LDS reads <=2-way
//     = free). LDS:VALU = 0.75 -> VALU-bound. Panels 2x155us, VALUBusy 50%,
//     HBM 10% -> issue/latency-bound; tail kernel = 104 MB C round-trip.
//   * R9: fuse P2+tail+bias into one kernel (tail chain computed row-wise in
//     epilogue, +8 regs only). Kills gemm1_tail's C round-trip + dispatch.
// ===========================================================================

// ---------------------------------------------------------------------------
// GEMM1 panel kernel (P1): k 0..383. BM=BN=128, BK=8, 256 threads = 4 waves
// in 2x2; each wave 8x8 lanes; micro 8x8. Double-buffered LDS, one barrier
// per iteration, prefetch-ahead. C = acc (overwrite).
// ---------------------------------------------------------------------------
#define BM 128
#define BN 128
#define BK 8
#define PANEL_K 384

__global__ __launch_bounds__(256) void gemm1_panel1(
    const float* __restrict__ X, const float* __restrict__ W,
    float* __restrict__ C)
{
    __shared__ float As[2][BK][BM + 4];   // 2 x 4224 B
    __shared__ float Bs[2][BK][BN + 4];   // 2 x 4224 B

    const int tid = threadIdx.x;
    const int bm  = blockIdx.x * BM;
    const int bn  = blockIdx.y * BN;

    // staging: 128 rows x 8 k = 256 float4
    const int row  = tid >> 1;           // 0..127
    const int koff = (tid & 1) * 4;      // 0 or 4

    // compute mapping: wave 2x2, lane 8x8, micro 8x8
    const int w    = tid >> 6;
    const int lane = tid & 63;
    const int tm   = (w & 1) * 64 + (lane & 7) * 8;    // 0..120
    const int tn   = (w >> 1) * 64 + (lane >> 3) * 8;  // 0..120

    float acc[8][8];
    #pragma unroll
    for (int i = 0; i < 8; ++i)
        #pragma unroll
        for (int j = 0; j < 8; ++j) acc[i][j] = 0.f;

    const float* Xp = X + (size_t)(bm + row) * NIN + koff;
    const float* Wp = W + (size_t)(bn + row) * NIN + koff;

    // prologue: stage iter 0 into buffer 0
    float4 pa = *(const float4*)(Xp);
    float4 pb = *(const float4*)(Wp);
    As[0][koff+0][row] = pa.x; As[0][koff+1][row] = pa.y;
    As[0][koff+2][row] = pa.z; As[0][koff+3][row] = pa.w;
    Bs[0][koff+0][row] = pb.x; Bs[0][koff+1][row] = pb.y;
    Bs[0][koff+2][row] = pb.z; Bs[0][koff+3][row] = pb.w;

    const int NITER = PANEL_K / BK;   // 48
    for (int it = 0; it < NITER; ++it) {
        const int cur = it & 1;
        __syncthreads();

        if (it + 1 < NITER) {
            const int k0 = (it + 1) * BK;
            pa = *(const float4*)(Xp + k0);
            pb = *(const float4*)(Wp + k0);
        }

        #pragma unroll
        for (int kk = 0; kk < BK; ++kk) {   // k ascending
            float4 av0 = *(const float4*)&As[cur][kk][tm];
            float4 av1 = *(const float4*)&As[cur][kk][tm + 4];
            float4 bv0 = *(const float4*)&Bs[cur][kk][tn];
            float4 bv1 = *(const float4*)&Bs[cur][kk][tn + 4];
            float a[8] = {av0.x, av0.y, av0.z, av0.w, av1.x, av1.y, av1.z, av1.w};
            float b[8] = {bv0.x, bv0.y, bv0.z, bv0.w, bv1.x, bv1.y, bv1.z, bv1.w};
            #pragma unroll
            for (int i = 0; i < 8; ++i)
                #pragma unroll
                for (int j = 0; j < 8; ++j)
                    acc[i][j] = fmaf(a[i], b[j], acc[i][j]);
        }

        if (it + 1 < NITER) {
            const int nxt = cur ^ 1;
            As[nxt][koff+0][row] = pa.x; As[nxt][koff+1][row] = pa.y;
            As[nxt][koff+2][row] = pa.z; As[nxt][koff+3][row] = pa.w;
            Bs[nxt][koff+0][row] = pb.x; Bs[nxt][koff+1][row] = pb.y;
            Bs[nxt][koff+2][row] = pb.z; Bs[nxt][koff+3][row] = pb.w;
        }
    }

    #pragma unroll
    for (int i = 0; i < 8; ++i) {
        size_t r = (size_t)(bm + tm + i) * NHID + bn + tn;
        *(float4*)&C[r]     = make_float4(acc[i][0], acc[i][1], acc[i][2], acc[i][3]);
        *(float4*)&C[r + 4] = make_float4(acc[i][4], acc[i][5], acc[i][6], acc[i][7]);
    }
}

// ---------------------------------------------------------------------------
// GEMM1 P2 + tail + bias, fused. Main loop: k 384..767 (identical structure
// to P1, acc2 chain). Epilogue: stage X/W k=768..783 into the two LDS
// buffers (As[0]=k768..775, As[1]=k776..783), then per output row compute
// the 16-k acc3 chain in 8 regs and fold:
//   C = fadd(fadd(fadd(C_P1, acc2), acc3), bias)
// Bit-identical to the previous gemm1_panel<true> + gemm1_tail pair.
// ---------------------------------------------------------------------------
__global__ __launch_bounds__(256) void gemm1_p2_tail(
    const float* __restrict__ X, const float* __restrict__ W,
    const float* __restrict__ bias, float* __restrict__ C)
{
    __shared__ float As[2][BK][BM + 4];
    __shared__ float Bs[2][BK][BN + 4];

    const int tid = threadIdx.x;
    const int bm  = blockIdx.x * BM;
    const int bn  = blockIdx.y * BN;

    const int row  = tid >> 1;           // 0..127
    const int koff = (tid & 1) * 4;      // 0 or 4

    const int w    = tid >> 6;
    const int lane = tid & 63;
    const int tm   = (w & 1) * 64 + (lane & 7) * 8;
    const int tn   = (w >> 1) * 64 + (lane >> 3) * 8;

    float acc[8][8];
    #pragma unroll
    for (int i = 0; i < 8; ++i)
        #pragma unroll
        for (int j = 0; j < 8; ++j) acc[i][j] = 0.f;

    const float* Xp = X + (size_t)(bm + row) * NIN + 384 + koff;
    const float* Wp = W + (size_t)(bn + row) * NIN + 384 + koff;

    float4 pa = *(const float4*)(Xp);
    float4 pb = *(const float4*)(Wp);
    As[0][koff+0][row] = pa.x; As[0][koff+1][row] = pa.y;
    As[0][koff+2][row] = pa.z; As[0][koff+3][row] = pa.w;
    Bs[0][koff+0][row] = pb.x; Bs[0][koff+1][row] = pb.y;
    Bs[0][koff+2][row] = pb.z; Bs[0][koff+3][row] = pb.w;

    const int NITER = PANEL_K / BK;   // 48
    for (int it = 0; it < NITER; ++it) {
        const int cur = it & 1;
        __syncthreads();

        if (it + 1 < NITER) {
            const int k0 = (it + 1) * BK;
            pa = *(const float4*)(Xp + k0);
            pb = *(const float4*)(Wp + k0);
        }

        #pragma unroll
        for (int kk = 0; kk < BK; ++kk) {   // k ascending (384..767)
            float4 av0 = *(const float4*)&As[cur][kk][tm];
            float4 av1 = *(const float4*)&As[cur][kk][tm + 4];
            float4 bv0 = *(const float4*)&Bs[cur][kk][tn];
            float4 bv1 = *(const float4*)&Bs[cur][kk][tn + 4];
            float a[8] = {av0.x, av0.y, av0.z, av0.w, av1.x, av1.y, av1.z, av1.w};
            float b[8] = {bv0.x, bv0.y, bv0.z, bv0.w, bv1.x, bv1.y, bv1.z, bv1.w};
            #pragma unroll
            for (int i = 0; i < 8; ++i)
                #pragma unroll
                for (int j = 0; j < 8; ++j)
                    acc[i][j] = fmaf(a[i], b[j], acc[i][j]);
        }

        if (it + 1 < NITER) {
            const int nxt = cur ^ 1;
            As[nxt][koff+0][row] = pa.x; As[nxt][koff+1][row] = pa.y;
            As[nxt][koff+2][row] = pa.z; As[nxt][koff+3][row] = pa.w;
            Bs[nxt][koff+0][row] = pb.x; Bs[nxt][koff+1][row] = pb.y;
            Bs[nxt][koff+2][row] = pb.z; Bs[nxt][koff+3][row] = pb.w;
        }
    }

    // ---- tail: stage k=768..783 into both LDS buffers -------------------
    __syncthreads();   // everyone done reading buffer (NITER-1)&1
    {
        const float* Xt = X + (size_t)(bm + row) * NIN + 768 + koff;
        const float* Wt = W + (size_t)(bn + row) * NIN + 768 + koff;
        float4 xa = *(const float4*)(Xt);        // k 768+koff .. +3
        float4 xb = *(const float4*)(Xt + 8);    // k 776+koff .. +3
        float4 wa = *(const float4*)(Wt);
        float4 wb = *(const float4*)(Wt + 8);
        As[0][koff+0][row] = xa.x; As[0][koff+1][row] = xa.y;
        As[0][koff+2][row] = xa.z; As[0][koff+3][row] = xa.w;
        As[1][koff+0][row] = xb.x; As[1][koff+1][row] = xb.y;
        As[1][koff+2][row] = xb.z; As[1][koff+3][row] = xb.w;
        Bs[0][koff+0][row] = wa.x; Bs[0][koff+1][row] = wa.y;
        Bs[0][koff+2][row] = wa.z; Bs[0][koff+3][row] = wa.w;
        Bs[1][koff+0][row] = wb.x; Bs[1][koff+1][row] = wb.y;
        Bs[1][koff+2][row] = wb.z; Bs[1][koff+3][row] = wb.w;
    }
    __syncthreads();

    float4 bi0 = *(const float4*)&bias[bn + tn];
    float4 bi1 = *(const float4*)&bias[bn + tn + 4];
    const float bi[8] = {bi0.x, bi0.y, bi0.z, bi0.w, bi1.x, bi1.y, bi1.z, bi1.w};

    #pragma unroll
    for (int i = 0; i < 8; ++i) {
        // acc3 chain for this row: 16 k ascending (768..783), 8 regs
        float ar[8] = {0.f, 0.f, 0.f, 0.f, 0.f, 0.f, 0.f, 0.f};
        #pragma unroll
        for (int kk = 0; kk < BK; ++kk) {       // k 768..775
            float a = As[0][kk][tm + i];
            float4 bv0 = *(const float4*)&Bs[0][kk][tn];
            float4 bv1 = *(const float4*)&Bs[0][kk][tn + 4];
            ar[0] = fmaf(a, bv0.x, ar[0]); ar[1] = fmaf(a, bv0.y, ar[1]);
            ar[2] = fmaf(a, bv0.z, ar[2]); ar[3] = fmaf(a, bv0.w, ar[3]);
            ar[4] = fmaf(a, bv1.x, ar[4]); ar[5] = fmaf(a, bv1.y, ar[5]);
            ar[6] = fmaf(a, bv1.z, ar[6]); ar[7] = fmaf(a, bv1.w, ar[7]);
        }
        #pragma unroll
        for (int kk = 0; kk < BK; ++kk) {       // k 776..783
            float a = As[1][kk][tm + i];
            float4 bv0 = *(const float4*)&Bs[1][kk][tn];
            float4 bv1 = *(const float4*)&Bs[1][kk][tn + 4];
            ar[0] = fmaf(a, bv0.x, ar[0]); ar[1] = fmaf(a, bv0.y, ar[1]);
            ar[2] = fmaf(a, bv0.z, ar[2]); ar[3] = fmaf(a, bv0.w, ar[3]);
            ar[4] = fmaf(a, bv1.x, ar[4]); ar[5] = fmaf(a, bv1.y, ar[5]);
            ar[6] = fmaf(a, bv1.z, ar[6]); ar[7] = fmaf(a, bv1.w, ar[7]);
        }

        size_t r = (size_t)(bm + tm + i) * NHID + bn + tn;
        float4 c0 = *(const float4*)&C[r];
        float4 c1 = *(const float4*)&C[r + 4];
        float4 o0, o1;
        o0.x = __fadd_rn(__fadd_rn(__fadd_rn(c0.x, acc[i][0]), ar[0]), bi[0]);
        o0.y = __fadd_rn(__fadd_rn(__fadd_rn(c0.y, acc[i][1]), ar[1]), bi[1]);
        o0.z = __fadd_rn(__fadd_rn(__fadd_rn(c0.z, acc[i][2]), ar[2]), bi[2]);
        o0.w = __fadd_rn(__fadd_rn(__fadd_rn(c0.w, acc[i][3]), ar[3]), bi[3]);
        o1.x = __fadd_rn(__fadd_rn(__fadd_rn(c1.x, acc[i][4]), ar[4]), bi[4]);
        o1.y = __fadd_rn(__fadd_rn(__fadd_rn(c1.y, acc[i][5]), ar[5]), bi[5]);
        o1.z = __fadd_rn(__fadd_rn(__fadd_rn(c1.z, acc[i][6]), ar[6]), bi[6]);
        o1.w = __fadd_rn(__fadd_rn(__fadd_rn(c1.w, acc[i][7]), ar[7]), bi[7]);
        *(float4*)&C[r]     = o0;
        *(float4*)&C[r + 4] = o1;
    }
}

// ---------------------------------------------------------------------------
// Hidden Leaky recurrence (fp32 _rn), scalar, depth-8 ring-buffer prefetch.
// 512 blocks x 256 threads = 131072 chains, fully resident. In place:
// mem_io holds cur1 on entry, mem1 on exit.
// ---------------------------------------------------------------------------
__global__ __launch_bounds__(256) void leaky_hidden_kernel(
    float* __restrict__ mem_io, float* __restrict__ spk_out)
{
    const int idx = blockIdx.x * blockDim.x + threadIdx.x;  // 0..131071
    const size_t STRIDE = (size_t)BATCH * NHID;

    float buf[8];
    #pragma unroll
    for (int i = 0; i < 8; ++i) buf[i] = mem_io[idx + (size_t)i * STRIDE];

    float mem = 0.f;
    #pragma unroll 4
    for (int t = 0; t < T_STEPS; ++t) {
        float cur = buf[t & 7];
        int tn = t + 8;
        if (tn < T_STEPS) buf[t & 7] = mem_io[idx + (size_t)tn * STRIDE];
        float rst = (mem > 1.0f) ? 1.0f : 0.0f;
        mem = __fsub_rn(__fadd_rn(__fmul_rn(0.95f, mem), cur), rst);
        size_t off = idx + (size_t)t * STRIDE;
        spk_out[off] = (mem > 1.0f) ? 1.0f : 0.0f;
        mem_io[off]  = mem;
    }
}

// ---------------------------------------------------------------------------
// GEMM2: cur2[m][o] = fl32( f64( sum_k spk1[m][k]*W2[o][k] + b2[o] ) )
// W2 (20 KB) staged in LDS. Block = 320 threads = 32 rows x 10 outputs.
// ---------------------------------------------------------------------------
#define G2_ROWS 32

__global__ __launch_bounds__(320) void gemm2_f64(
    const float* __restrict__ spk1, const float* __restrict__ W2,
    const float* __restrict__ b2, float* __restrict__ cur2)
{
    __shared__ float w2s[NOUT * NHID];  // 20 KB
    const int tid = threadIdx.x;
    for (int i = tid; i < NOUT * NHID; i += 320) w2s[i] = W2[i];
    __syncthreads();

    const int r = tid / NOUT;   // 0..31
    const int o = tid % NOUT;   // 0..9
    const size_t m = (size_t)blockIdx.x * G2_ROWS + r;
    const float* rowp = spk1 + m * NHID;
    const float* wp   = w2s + o * NHID;
    double dot = 0.0;
    #pragma unroll 4
    for (int k = 0; k < NHID; k += 4) {
        float4 s  = *(const float4*)(rowp + k);
        float4 wv = *(const float4*)(wp + k);
        dot = fma((double)s.x, (double)wv.x, dot);
        dot = fma((double)s.y, (double)wv.y, dot);
        dot = fma((double)s.z, (double)wv.z, dot);
        dot = fma((double)s.w, (double)wv.w, dot);
    }
    cur2[m * NOUT + o] = (float)(dot + (double)b2[o]);   // coalesced
}

// ---------------------------------------------------------------------------
// Output Leaky recurrence (fp32 _rn): one thread per (b,o) chain (2560).
// ---------------------------------------------------------------------------
__global__ __launch_bounds__(256) void leaky_out_kernel(
    const float* __restrict__ cur2, float* __restrict__ spk2,
    float* __restrict__ mem2)
{
    const int idx = blockIdx.x * blockDim.x + threadIdx.x;
    if (idx >= BATCH * NOUT) return;
    const int STRIDE = BATCH * NOUT;

    float buf[8];
    #pragma unroll
    for (int i = 0; i < 8; ++i) buf[i] = cur2[(size_t)i * STRIDE + idx];

    float mem = 0.f;
    #pragma unroll 4
    for (int t = 0; t < T_STEPS; ++t) {
        float cur = buf[t & 7];
        int tn = t + 8;
        if (tn < T_STEPS) buf[t & 7] = cur2[(size_t)tn * STRIDE + idx];
        float rst = (mem > 1.0f) ? 1.0f : 0.0f;
        mem = __fsub_rn(__fadd_rn(__fmul_rn(0.95f, mem), cur), rst);
        size_t off = (size_t)t * STRIDE + idx;
        spk2[off] = (mem > 1.0f) ? 1.0f : 0.0f;
        mem2[off] = mem;
    }
}

// ---------------------------------------------------------------------------
extern "C" void kernel_launch(void* const* d_in, const int* in_sizes, int n_in,
                              void* d_out, int out_size, void* d_ws, size_t ws_size,
                              hipStream_t stream) {
    const float* x  = (const float*)d_in[0];   // (100, 256, 784)
    const float* w1 = (const float*)d_in[1];   // (512, 784)
    const float* b1 = (const float*)d_in[2];   // (512,)
    const float* w2 = (const float*)d_in[3];   // (10, 512)
    const float* b2 = (const float*)d_in[4];   // (10,)

    float* out = (float*)d_out;
    // Output tuple order: (cur2, spk2, spk1, mem2, mem1), each stacked over T.
    float* cur2_out = out;                       // 256000
    float* spk2_out = out + 256000;              // 256000
    float* spk1_out = out + 512000;              // 13107200
    float* mem2_out = out + 13619200;            // 256000
    float* mem1_out = out + 13875200;            // 13107200

    const int M = T_STEPS * BATCH;               // 25600

    // 1) cur1 = X @ W1^T + b1 via 2 launches into the mem1 region.
    dim3 gp(M / BM, NHID / BN);                  // (200, 4)
    gemm1_panel1<<<gp, 256, 0, stream>>>(x, w1, mem1_out);
    gemm1_p2_tail<<<gp, 256, 0, stream>>>(x, w1, b1, mem1_out);

    // 2) hidden Leaky chains (fp32 _rn, scalar ring-buffer):
    leaky_hidden_kernel<<<(BATCH * NHID) / 256, 256, 0, stream>>>(mem1_out, spk1_out);

    // 3) cur2 = spk1 @ W2^T + b2 (f64 acc -> fp32)
    gemm2_f64<<<M / G2_ROWS, 320, 0, stream>>>(spk1_out, w2, b2, cur2_out);

    // 4) output Leaky chains (fp32 _rn): cur2 -> (spk2, mem2)
    leaky_out_kernel<<<(BATCH * NOUT + 255) / 256, 256, 0, stream>>>(
        cur2_out, spk2_out, mem2_out);
}

// Round 4
// 542.820 us; speedup vs baseline: 1.1877x; 1.1877x over previous
//
#include <hip/hip_runtime.h>
#include <stdint.h>

#define T_STEPS 100
#define BATCH   256
#define NIN     784
#define NHID    512
#define NOUT    10

// ===========================================================================
// NUMERICS CONTRACT (validated PASS R5/R6/R7 — do not break):
//   * gemm1: per C element, fp32 single-accumulator fmaf chain, k ascending,
//     OpenBLAS kc=384 panel folds: cur1 = ((P1 + P2) + P3) + bias, each +
//     a single __fadd_rn. Realized here as:
//       gemm1_dual z=0: C1 = acc(k 0..383)      (pure write, mem1 region)
//       gemm1_dual z=1: C2 = acc(k 384..767)    (pure write, d_ws scratch)
//       leaky_hidden_fused: cur = fadd(fadd(fadd(C1,C2),acc3),b1), where
//         acc3 = 16-k ascending fmaf chain (k 768..783) computed in-register.
//     Op-for-op identical to the validated 3-launch P1/P2/tail version.
//   * gemm2: f64 accumulation of fp32 products, +b2 in f64, single rounding.
//   * recurrences: fp32 _rn ops, ((0.95*mem + cur) - rst), no contraction;
//     spike/reset = (mem > 1.0f).
// PERF JOURNAL:
//   * R5 570us: 8x8 single-buf, VALUBusy 36%, latency-bound (2 waves/SIMD).
//   * R6 2144us: __launch_bounds__(256,3) clamped VGPR->84, scratch spill,
//     9.5 GB HBM. Never use min-waves arg near the register boundary.
//   * R7 453us: dbuf 8x4, VGPR 148, VALUBusy 38% — LDS-pipe bound.
//   * R8 582us: 3-launch panel split -> 8x8 micro, BK=8, AGPR-clean acc
//     (VGPR 56!), panels 2x155us, VALUBusy 50%, HBM 10%.
//   * R9 645us REGRESSION: fusing tail into P2's epilogue broke the AGPR
//     allocation of acc[8][8] (VGPR 56->204, occ 22->9%, 155->249us).
//     LESSON: never touch acc non-trivially in the GEMM epilogue.
//   * R10/R11: P1/P2 pure-write panels (one z=2 launch); tail fold + bias
//     moved into leaky_hidden. Both rounds died on container acquisition
//     (no pytest verdict, no counters). Source audited clean (bounds,
//     overwrite, graph rules).
//   * R12: hedge — P2 scratch moved from spk1-region aliasing to d_ws
//     workspace (52.4 MB) when available; removes the one exotic feature
//     (same-buffer read/write streaming) at zero cost. Fallback to spk1
//     aliasing only if ws_size too small.
// ===========================================================================

// ---------------------------------------------------------------------------
// GEMM1 dual-panel kernel: z=0 -> k 0..383 into C1; z=1 -> k 384..767 into
// C2. BM=BN=128, BK=8, 256 threads = 4 waves in 2x2; each wave 8x8 lanes;
// micro 8x8. Double-buffered LDS, one barrier per iteration, prefetch-ahead.
// Pure overwrite, epilogue untouched (keeps acc in AGPRs, VGPR ~56).
// ---------------------------------------------------------------------------
#define BM 128
#define BN 128
#define BK 8
#define PANEL_K 384

__global__ __launch_bounds__(256) void gemm1_dual(
    const float* __restrict__ X, const float* __restrict__ W,
    float* __restrict__ C1, float* __restrict__ C2)
{
    __shared__ float As[2][BK][BM + 4];   // 2 x 4224 B
    __shared__ float Bs[2][BK][BN + 4];   // 2 x 4224 B

    const int tid = threadIdx.x;
    const int bm  = blockIdx.x * BM;
    const int bn  = blockIdx.y * BN;
    const int kb  = blockIdx.z ? PANEL_K : 0;
    float* __restrict__ C = blockIdx.z ? C2 : C1;

    // staging: 128 rows x 8 k = 256 float4
    const int row  = tid >> 1;           // 0..127
    const int koff = (tid & 1) * 4;      // 0 or 4

    // compute mapping: wave 2x2, lane 8x8, micro 8x8
    const int w    = tid >> 6;
    const int lane = tid & 63;
    const int tm   = (w & 1) * 64 + (lane & 7) * 8;    // 0..120
    const int tn   = (w >> 1) * 64 + (lane >> 3) * 8;  // 0..120

    float acc[8][8];
    #pragma unroll
    for (int i = 0; i < 8; ++i)
        #pragma unroll
        for (int j = 0; j < 8; ++j) acc[i][j] = 0.f;

    const float* Xp = X + (size_t)(bm + row) * NIN + kb + koff;
    const float* Wp = W + (size_t)(bn + row) * NIN + kb + koff;

    // prologue: stage iter 0 into buffer 0
    float4 pa = *(const float4*)(Xp);
    float4 pb = *(const float4*)(Wp);
    As[0][koff+0][row] = pa.x; As[0][koff+1][row] = pa.y;
    As[0][koff+2][row] = pa.z; As[0][koff+3][row] = pa.w;
    Bs[0][koff+0][row] = pb.x; Bs[0][koff+1][row] = pb.y;
    Bs[0][koff+2][row] = pb.z; Bs[0][koff+3][row] = pb.w;

    const int NITER = PANEL_K / BK;   // 48
    for (int it = 0; it < NITER; ++it) {
        const int cur = it & 1;
        __syncthreads();

        if (it + 1 < NITER) {
            const int k0 = (it + 1) * BK;
            pa = *(const float4*)(Xp + k0);
            pb = *(const float4*)(Wp + k0);
        }

        #pragma unroll
        for (int kk = 0; kk < BK; ++kk) {   // k ascending
            float4 av0 = *(const float4*)&As[cur][kk][tm];
            float4 av1 = *(const float4*)&As[cur][kk][tm + 4];
            float4 bv0 = *(const float4*)&Bs[cur][kk][tn];
            float4 bv1 = *(const float4*)&Bs[cur][kk][tn + 4];
            float a[8] = {av0.x, av0.y, av0.z, av0.w, av1.x, av1.y, av1.z, av1.w};
            float b[8] = {bv0.x, bv0.y, bv0.z, bv0.w, bv1.x, bv1.y, bv1.z, bv1.w};
            #pragma unroll
            for (int i = 0; i < 8; ++i)
                #pragma unroll
                for (int j = 0; j < 8; ++j)
                    acc[i][j] = fmaf(a[i], b[j], acc[i][j]);
        }

        if (it + 1 < NITER) {
            const int nxt = cur ^ 1;
            As[nxt][koff+0][row] = pa.x; As[nxt][koff+1][row] = pa.y;
            As[nxt][koff+2][row] = pa.z; As[nxt][koff+3][row] = pa.w;
            Bs[nxt][koff+0][row] = pb.x; Bs[nxt][koff+1][row] = pb.y;
            Bs[nxt][koff+2][row] = pb.z; Bs[nxt][koff+3][row] = pb.w;
        }
    }

    #pragma unroll
    for (int i = 0; i < 8; ++i) {
        size_t r = (size_t)(bm + tm + i) * NHID + bn + tn;
        *(float4*)&C[r]     = make_float4(acc[i][0], acc[i][1], acc[i][2], acc[i][3]);
        *(float4*)&C[r + 4] = make_float4(acc[i][4], acc[i][5], acc[i][6], acc[i][7]);
    }
}

// ---------------------------------------------------------------------------
// Hidden Leaky recurrence, fused with the GEMM1 tail fold:
//   cur = fadd(fadd(fadd(P1, P2), acc3), b1)     [acc3 = 16-k fmaf chain]
//   mem = fsub(fadd(fmul(0.95, mem), cur), rst)
// One thread per (b,h) chain (131072). Depth-8 ring prefetch on BOTH partial
// streams. c2/spk_out NOT __restrict__: in the fallback path (tiny ws) they
// alias; ring reads [t+8] precede spike writes [t+8] in program order, same
// thread-column, so ordering is correct either way. W1 tail row lives in 16
// regs; X tail (64 B, uniform per block) is an L1 broadcast, prefetched one
// step ahead.
// ---------------------------------------------------------------------------
__global__ __launch_bounds__(256) void leaky_hidden_fused(
    float* __restrict__ mem_io,        // P1 on entry, mem1 on exit
    const float* c2,                   // P2 partial (may alias spk_out)
    float* spk_out,
    const float* __restrict__ X,
    const float* __restrict__ W1,
    const float* __restrict__ b1)
{
    const int idx = blockIdx.x * blockDim.x + threadIdx.x;  // 0..131071
    const size_t STRIDE = (size_t)BATCH * NHID;
    const int h  = idx & (NHID - 1);
    const int bb = idx >> 9;

    // W1[h][768..783] -> 16 regs
    const float* wp = W1 + (size_t)h * NIN + 768;
    float4 w0 = *(const float4*)(wp);
    float4 w1v = *(const float4*)(wp + 4);
    float4 w2v = *(const float4*)(wp + 8);
    float4 w3v = *(const float4*)(wp + 12);
    const float wt[16] = {w0.x, w0.y, w0.z, w0.w, w1v.x, w1v.y, w1v.z, w1v.w,
                          w2v.x, w2v.y, w2v.z, w2v.w, w3v.x, w3v.y, w3v.z, w3v.w};
    const float bias = b1[h];

    // X tail base for this thread's batch row; stride BATCH*NIN per t
    const size_t XT_STRIDE = (size_t)BATCH * NIN;
    const float* xb = X + (size_t)bb * NIN + 768;

    float buf1[8], buf2[8];
    #pragma unroll
    for (int i = 0; i < 8; ++i) {
        buf1[i] = mem_io[idx + (size_t)i * STRIDE];
        buf2[i] = c2[idx + (size_t)i * STRIDE];
    }

    // prefetch X tail for t=0
    float4 xa0 = *(const float4*)(xb);
    float4 xa1 = *(const float4*)(xb + 4);
    float4 xa2 = *(const float4*)(xb + 8);
    float4 xa3 = *(const float4*)(xb + 12);

    float mem = 0.f;
    for (int t = 0; t < T_STEPS; ++t) {
        const float p1 = buf1[t & 7];
        const float p2 = buf2[t & 7];
        const float xt[16] = {xa0.x, xa0.y, xa0.z, xa0.w, xa1.x, xa1.y, xa1.z, xa1.w,
                              xa2.x, xa2.y, xa2.z, xa2.w, xa3.x, xa3.y, xa3.z, xa3.w};

        const int tn = t + 8;
        if (tn < T_STEPS) {
            buf1[t & 7] = mem_io[idx + (size_t)tn * STRIDE];
            buf2[t & 7] = c2[idx + (size_t)tn * STRIDE];
        }
        if (t + 1 < T_STEPS) {
            const float* xn = xb + (size_t)(t + 1) * XT_STRIDE;
            xa0 = *(const float4*)(xn);
            xa1 = *(const float4*)(xn + 4);
            xa2 = *(const float4*)(xn + 8);
            xa3 = *(const float4*)(xn + 12);
        }

        // P3: 16-k ascending single-accumulator fmaf chain (bit-identical
        // to the old gemm1_tail acc chain).
        float acc3 = 0.f;
        #pragma unroll
        for (int kk = 0; kk < 16; ++kk)
            acc3 = fmaf(xt[kk], wt[kk], acc3);

        const float cur = __fadd_rn(__fadd_rn(__fadd_rn(p1, p2), acc3), bias);
        const float rst = (mem > 1.0f) ? 1.0f : 0.0f;
        mem = __fsub_rn(__fadd_rn(__fmul_rn(0.95f, mem), cur), rst);

        const size_t off = idx + (size_t)t * STRIDE;
        spk_out[off] = (mem > 1.0f) ? 1.0f : 0.0f;
        mem_io[off]  = mem;
    }
}

// ---------------------------------------------------------------------------
// GEMM2: cur2[m][o] = fl32( f64( sum_k spk1[m][k]*W2[o][k] + b2[o] ) )
// W2 (20 KB) staged in LDS. Block = 320 threads = 32 rows x 10 outputs.
// ---------------------------------------------------------------------------
#define G2_ROWS 32

__global__ __launch_bounds__(320) void gemm2_f64(
    const float* __restrict__ spk1, const float* __restrict__ W2,
    const float* __restrict__ b2, float* __restrict__ cur2)
{
    __shared__ float w2s[NOUT * NHID];  // 20 KB
    const int tid = threadIdx.x;
    for (int i = tid; i < NOUT * NHID; i += 320) w2s[i] = W2[i];
    __syncthreads();

    const int r = tid / NOUT;   // 0..31
    const int o = tid % NOUT;   // 0..9
    const size_t m = (size_t)blockIdx.x * G2_ROWS + r;
    const float* rowp = spk1 + m * NHID;
    const float* wp   = w2s + o * NHID;
    double dot = 0.0;
    #pragma unroll 4
    for (int k = 0; k < NHID; k += 4) {
        float4 s  = *(const float4*)(rowp + k);
        float4 wv = *(const float4*)(wp + k);
        dot = fma((double)s.x, (double)wv.x, dot);
        dot = fma((double)s.y, (double)wv.y, dot);
        dot = fma((double)s.z, (double)wv.z, dot);
        dot = fma((double)s.w, (double)wv.w, dot);
    }
    cur2[m * NOUT + o] = (float)(dot + (double)b2[o]);   // coalesced
}

// ---------------------------------------------------------------------------
// Output Leaky recurrence (fp32 _rn): one thread per (b,o) chain (2560).
// ---------------------------------------------------------------------------
__global__ __launch_bounds__(256) void leaky_out_kernel(
    const float* __restrict__ cur2, float* __restrict__ spk2,
    float* __restrict__ mem2)
{
    const int idx = blockIdx.x * blockDim.x + threadIdx.x;
    if (idx >= BATCH * NOUT) return;
    const int STRIDE = BATCH * NOUT;

    float buf[8];
    #pragma unroll
    for (int i = 0; i < 8; ++i) buf[i] = cur2[(size_t)i * STRIDE + idx];

    float mem = 0.f;
    #pragma unroll 4
    for (int t = 0; t < T_STEPS; ++t) {
        float cur = buf[t & 7];
        int tn = t + 8;
        if (tn < T_STEPS) buf[t & 7] = cur2[(size_t)tn * STRIDE + idx];
        float rst = (mem > 1.0f) ? 1.0f : 0.0f;
        mem = __fsub_rn(__fadd_rn(__fmul_rn(0.95f, mem), cur), rst);
        size_t off = (size_t)t * STRIDE + idx;
        spk2[off] = (mem > 1.0f) ? 1.0f : 0.0f;
        mem2[off] = mem;
    }
}

// ---------------------------------------------------------------------------
extern "C" void kernel_launch(void* const* d_in, const int* in_sizes, int n_in,
                              void* d_out, int out_size, void* d_ws, size_t ws_size,
                              hipStream_t stream) {
    const float* x  = (const float*)d_in[0];   // (100, 256, 784)
    const float* w1 = (const float*)d_in[1];   // (512, 784)
    const float* b1 = (const float*)d_in[2];   // (512,)
    const float* w2 = (const float*)d_in[3];   // (10, 512)
    const float* b2 = (const float*)d_in[4];   // (10,)

    float* out = (float*)d_out;
    // Output tuple order: (cur2, spk2, spk1, mem2, mem1), each stacked over T.
    float* cur2_out = out;                       // 256000
    float* spk2_out = out + 256000;              // 256000
    float* spk1_out = out + 512000;              // 13107200
    float* mem2_out = out + 13619200;            // 256000
    float* mem1_out = out + 13875200;            // 13107200

    const int M = T_STEPS * BATCH;               // 25600

    // P2 scratch: prefer d_ws (no aliasing); fall back to spk1 region
    // (per-thread-column safe aliasing) only if workspace is too small.
    const size_t p2_bytes = (size_t)M * NHID * sizeof(float);   // 52.4 MB
    float* p2buf = (d_ws != nullptr && ws_size >= p2_bytes)
                       ? (float*)d_ws : spk1_out;

    // 1) P1 -> mem1 region, P2 -> p2buf, one z=2 launch.
    dim3 gp(M / BM, NHID / BN, 2);               // (200, 4, 2) = 1600 blocks
    gemm1_dual<<<gp, 256, 0, stream>>>(x, w1, mem1_out, p2buf);

    // 2) hidden Leaky chains + P3 tail fold + bias (fp32 _rn):
    //    reads P1 (mem1 region) + P2 (p2buf), writes mem1 + spk1.
    leaky_hidden_fused<<<(BATCH * NHID) / 256, 256, 0, stream>>>(
        mem1_out, p2buf, spk1_out, x, w1, b1);

    // 3) cur2 = spk1 @ W2^T + b2 (f64 acc -> fp32)
    gemm2_f64<<<M / G2_ROWS, 320, 0, stream>>>(spk1_out, w2, b2, cur2_out);

    // 4) output Leaky chains (fp32 _rn): cur2 -> (spk2, mem2)
    leaky_out_kernel<<<(BATCH * NOUT + 255) / 256, 256, 0, stream>>>(
        cur2_out, spk2_out, mem2_out);
}